// Round 2
// baseline (160.400 us; speedup 1.0000x reference)
//
#include <hip/hip_runtime.h>
#include <stdint.h>

// Binary BasicBlock: x ->(sign) conv1 ->BN1 ->(sign) conv2 ->BN2 -> +x
// B=64, C=256, H=W=28.  M = 64*784 = 50176 output pixels, N = 256, K = 9*256.
// Convs done as exact i8 MFMA implicit-GEMM (binarized values in {-1,0,1},
// integer accum <= 2304 -> bit-exact vs f32 reference). Conv biases b1/b2
// cancel inside training-mode BN (mean subtraction) and are dropped.

#define HW    784
#define MTOT  50176
#define BM    128
#define BN    128
#define MT    392          // MTOT/BM
#define NBLK  784          // MT * (256/BN)

typedef int   i32x4  __attribute__((ext_vector_type(4)));
typedef short shortx8 __attribute__((ext_vector_type(8)));
typedef float floatx4 __attribute__((ext_vector_type(4)));

typedef __attribute__((address_space(1))) const void gvoid_t;
typedef __attribute__((address_space(3))) void       lvoid_t;

__device__ __forceinline__ void gload16(const void* g, void* l) {
  // async global->LDS, 16B/lane; LDS dest = wave-uniform base + lane*16
  __builtin_amdgcn_global_load_lds((gvoid_t*)g, (lvoid_t*)l, 16, 0, 0);
}

// ---------------------------------------------------------------- zero page
__global__ void zero4k(floatx4* p) { p[threadIdx.x] = (floatx4){0.f, 0.f, 0.f, 0.f}; }

// ---------------------------------------------------------------- binarize w
// w OIHW [256][256][3][3] -> wb [n][k], k = tap*256 + c  (tap = ky*3+kx)
__global__ __launch_bounds__(256) void bin_w(const float* __restrict__ w,
                                             int8_t* __restrict__ wb) {
  int idx = blockIdx.x * 256 + threadIdx.x;      // < 589824
  int n = idx / 2304;
  int k = idx - n * 2304;
  int tap = k >> 8;
  int c = k & 255;
  float v = w[((size_t)n * 256 + c) * 9 + tap];
  wb[idx] = (int8_t)((v > 0.f) - (v < 0.f));
}

// ---------------------------------------------------------------- binarize x
// x NCHW f32 -> xb NHWC i8 via LDS transpose tile (64 m x 64 c)
__global__ __launch_bounds__(256) void bin_x(const float* __restrict__ x,
                                             int8_t* __restrict__ xb) {
  const int mt = blockIdx.x, ct = blockIdx.y;
  __shared__ int8_t sh[64][68];
  const int t = threadIdx.x;
  const int tl = t & 63, th = t >> 6;
#pragma unroll
  for (int i = 0; i < 16; ++i) {
    int cl = th + i * 4;
    int c = ct * 64 + cl;
    int m = mt * 64 + tl;
    int b = m / HW, p = m - b * HW;
    float v = x[((size_t)b * 256 + c) * HW + p];   // coalesced along p
    sh[tl][cl] = (int8_t)((v > 0.f) - (v < 0.f));
  }
  __syncthreads();
#pragma unroll
  for (int i = 0; i < 16; ++i) {
    int ml = th + i * 4;
    xb[(size_t)(mt * 64 + ml) * 256 + ct * 64 + tl] = sh[ml][tl];  // 64B/wave-row
  }
}

// ---------------------------------------------------------------- conv (MFMA)
// xb [M][256] i8 NHWC, wb [256][2304] i8 -> y [M][256] i16 NHWC
// + per-(mtile,wave_m) channel partial sum / sumsq (exact i32, no atomics)
__global__ __launch_bounds__(256, 2) void bconv_mfma(
    const int8_t* __restrict__ xb, const int8_t* __restrict__ wb,
    int16_t* __restrict__ y, int* __restrict__ ssum, int* __restrict__ ssq,
    const int8_t* __restrict__ zp) {
  __shared__ int8_t lds[65536];                 // A tile 32KB | B tile 32KB
  const int tid = threadIdx.x;
  const int lane = tid & 63;
  const int wv = tid >> 6;                      // 4 waves
  const int wm = wv >> 1, wn = wv & 1;          // 2x2 wave grid, 64x64 each
  const int l15 = lane & 15;
  const int l4 = lane >> 4;

  // XCD swizzle: 784 = 8*98 exactly; consecutive mtiles per XCD
  int bid = blockIdx.x;
  int nb = (bid & 7) * (NBLK / 8) + (bid >> 3);
  const int mtile = nb >> 1, ntile = nb & 1;
  const int m0 = mtile * BM, n0 = ntile * BN;

  // staging precompute (row r = wv*32 + j*4 + l4; lane block = l15)
  int pyv[8], pxv[8], soff[8], ldso[8];
  size_t pixb[8];
  const int8_t* wsrc[8];
#pragma unroll
  for (int j = 0; j < 8; ++j) {
    int r = wv * 32 + j * 4 + l4;
    int m = m0 + r;
    int b = m / HW;
    int p = m - b * HW;
    pyv[j] = p / 28;
    pxv[j] = p - pyv[j] * 28;
    pixb[j] = (size_t)b * HW;
    soff[j] = (l15 ^ (r & 7)) << 4;             // inverse-swizzled source block
    wsrc[j] = wb + (size_t)(n0 + r) * 2304 + soff[j];
    ldso[j] = (wv * 32 + j * 4) * 256;          // wave-uniform LDS base
  }

  i32x4 acc[4][4];
#pragma unroll
  for (int a = 0; a < 4; ++a)
#pragma unroll
    for (int b = 0; b < 4; ++b) acc[a][b] = (i32x4){0, 0, 0, 0};

  for (int tap = 0; tap < 9; ++tap) {
    const int dy = tap / 3 - 1, dx = tap % 3 - 1;
    // stage A (128 x 256 i8): OOB pixel rows read the zero page (= conv padding)
#pragma unroll
    for (int j = 0; j < 8; ++j) {
      int yy = pyv[j] + dy, xx = pxv[j] + dx;
      const int8_t* src = ((unsigned)yy < 28u && (unsigned)xx < 28u)
              ? xb + ((pixb[j] + yy * 28 + xx) << 8) + soff[j]
              : zp + soff[j];
      gload16(src, lds + ldso[j]);
    }
    // stage B (128 x 256 i8)
#pragma unroll
    for (int j = 0; j < 8; ++j)
      gload16(wsrc[j] + tap * 256, lds + 32768 + ldso[j]);
    __syncthreads();                            // drains vmcnt(0)

#pragma unroll
    for (int cc = 0; cc < 4; ++cc) {            // K chunks of 64 within tap
      i32x4 af[4], bf[4];
      const int bc = cc * 4 + l4;
#pragma unroll
      for (int rb = 0; rb < 4; ++rb) {
        int row = wm * 64 + rb * 16 + l15;
        af[rb] = *(const i32x4*)(lds + row * 256 + ((bc ^ (row & 7)) << 4));
      }
#pragma unroll
      for (int nf = 0; nf < 4; ++nf) {
        int row = wn * 64 + nf * 16 + l15;
        bf[nf] = *(const i32x4*)(lds + 32768 + row * 256 + ((bc ^ (row & 7)) << 4));
      }
#pragma unroll
      for (int nf = 0; nf < 4; ++nf)
#pragma unroll
        for (int rb = 0; rb < 4; ++rb)
          acc[nf][rb] = __builtin_amdgcn_mfma_i32_16x16x64_i8(af[rb], bf[nf],
                                                              acc[nf][rb], 0, 0, 0);
    }
    __syncthreads();
  }

  // epilogue: store y (i16 NHWC) + exact per-channel partials
  int sum_l[4] = {0, 0, 0, 0}, sq_l[4] = {0, 0, 0, 0};
#pragma unroll
  for (int nf = 0; nf < 4; ++nf) {
    const int n = n0 + wn * 64 + nf * 16 + l15;   // C/D: col = lane&15 (m89)
#pragma unroll
    for (int rb = 0; rb < 4; ++rb) {
      const int mb = m0 + wm * 64 + rb * 16 + l4 * 4;  // row = (lane>>4)*4 + j
#pragma unroll
      for (int j = 0; j < 4; ++j) {
        int v = acc[nf][rb][j];
        y[(size_t)(mb + j) * 256 + n] = (int16_t)v;
        sum_l[nf] += v;
        sq_l[nf] += v * v;                        // <= 16*2304^2, fits i32
      }
    }
  }
#pragma unroll
  for (int nf = 0; nf < 4; ++nf) {
    int s = sum_l[nf], q = sq_l[nf];
    s += __shfl_xor(s, 16); q += __shfl_xor(q, 16);
    s += __shfl_xor(s, 32); q += __shfl_xor(q, 32);
    if (lane < 16) {
      size_t off = (size_t)(mtile * 2 + wm) * 256 + (n0 + wn * 64 + nf * 16 + lane);
      ssum[off] = s;                              // unique writer per slot
      ssq[off] = q;
    }
  }
}

// ---------------------------------------------------------------- BN params
// reduce [MT*2][256] partials -> per-channel mean & gamma*rsqrt(var+eps)
__global__ __launch_bounds__(256) void bn_params(const int* __restrict__ ssum,
                                                 const int* __restrict__ ssq,
                                                 const float* __restrict__ gamma,
                                                 float* __restrict__ params) {
  const int c = blockIdx.x;
  const int t = threadIdx.x;
  long long s = 0, q = 0;
  for (int e = t; e < MT * 2; e += 256) {
    s += ssum[(size_t)e * 256 + c];
    q += ssq[(size_t)e * 256 + c];
  }
  __shared__ long long sh[8];
  for (int off = 32; off; off >>= 1) { s += __shfl_down(s, off); q += __shfl_down(q, off); }
  int wv = t >> 6;
  if ((t & 63) == 0) { sh[wv] = s; sh[wv + 4] = q; }
  __syncthreads();
  if (t == 0) {
    s = sh[0] + sh[1] + sh[2] + sh[3];
    q = sh[4] + sh[5] + sh[6] + sh[7];
    double mean = (double)s / (double)MTOT;
    double var = (double)q / (double)MTOT - mean * mean;
    params[c * 2 + 0] = (float)mean;
    params[c * 2 + 1] = (float)((double)gamma[c] / sqrt(var + 1e-5));
  }
}

// ---------------------------------------------------------------- binarize mid
// xb = sign((y - mean)*inv + beta)   (bias cancels in BN)
__global__ __launch_bounds__(256) void bin_mid(const int16_t* __restrict__ y,
                                               const float* __restrict__ params,
                                               const float* __restrict__ beta,
                                               int8_t* __restrict__ xb) {
  size_t i = ((size_t)blockIdx.x * 256 + threadIdx.x) * 8;
  shortx8 v = *(const shortx8*)(y + i);
  int cb = (int)(i & 255);
  union { int8_t b[8]; unsigned long long u; } o;
#pragma unroll
  for (int j = 0; j < 8; ++j) {
    int c = cb + j;
    float z = ((float)v[j] - params[c * 2]) * params[c * 2 + 1] + beta[c];
    o.b[j] = (int8_t)((z > 0.f) - (z < 0.f));
  }
  *(unsigned long long*)(xb + i) = o.u;
}

// ---------------------------------------------------------------- BN2 + resid
// out NCHW f32 = (y2 - mean)*inv + beta + x ; y2 read NHWC via LDS transpose
__global__ __launch_bounds__(256) void bn_residual(const int16_t* __restrict__ y,
                                                   const float* __restrict__ params,
                                                   const float* __restrict__ beta,
                                                   const float* __restrict__ x,
                                                   float* __restrict__ out) {
  const int mt = blockIdx.x, ct = blockIdx.y;
  __shared__ int16_t sh[64][66];
  const int t = threadIdx.x;
  const int tl = t & 63, th = t >> 6;
#pragma unroll
  for (int i = 0; i < 16; ++i) {
    int ml = th + i * 4;
    sh[ml][tl] = y[(size_t)(mt * 64 + ml) * 256 + ct * 64 + tl];  // coalesced
  }
  __syncthreads();
#pragma unroll
  for (int i = 0; i < 16; ++i) {
    int cl = th + i * 4;
    int c = ct * 64 + cl;
    int m = mt * 64 + tl;
    int b = m / HW, p = m - b * HW;
    size_t oi = ((size_t)b * 256 + c) * HW + p;
    float z = ((float)sh[tl][cl] - params[c * 2]) * params[c * 2 + 1] + beta[c];
    out[oi] = z + x[oi];                         // coalesced along p
  }
}

// ---------------------------------------------------------------- launch
extern "C" void kernel_launch(void* const* d_in, const int* in_sizes, int n_in,
                              void* d_out, int out_size, void* d_ws, size_t ws_size,
                              hipStream_t stream) {
  const float* x      = (const float*)d_in[0];
  const float* w1     = (const float*)d_in[1];
  const float* gamma1 = (const float*)d_in[3];
  const float* beta1  = (const float*)d_in[4];
  const float* w2     = (const float*)d_in[5];
  const float* gamma2 = (const float*)d_in[7];
  const float* beta2  = (const float*)d_in[8];
  float* out = (float*)d_out;

  // ws layout (bytes):
  char* ws = (char*)d_ws;
  int8_t*  zp      = (int8_t*)ws;                       //        0 : 4096 zero page
  int8_t*  wb1     = (int8_t*)(ws + 4096);              //   589824
  int8_t*  wb2     = (int8_t*)(ws + 593920);            //   589824
  float*   params1 = (float*)(ws + 1183744);            //     2048
  float*   params2 = (float*)(ws + 1185792);            //     2048
  int*     ssum    = (int*)(ws + 1187840);              //   802816
  int*     ssq     = (int*)(ws + 1990656);              //   802816
  int8_t*  xb      = (int8_t*)(ws + 2793472);           // 12845056 (reused conv1/conv2 input)
  int16_t* yb      = (int16_t*)(ws + 15638528);         // 25690112 (reused y1/y2)
  if (ws_size < 41328640ull) return;                    // need ~39.4 MiB scratch

  dim3 tr(784, 4);
  zero4k<<<1, 256, 0, stream>>>((floatx4*)zp);          // exactly 4096 B, every launch
  bin_w<<<2304, 256, 0, stream>>>(w1, wb1);
  bin_w<<<2304, 256, 0, stream>>>(w2, wb2);
  bin_x<<<tr, 256, 0, stream>>>(x, xb);
  bconv_mfma<<<NBLK, 256, 0, stream>>>(xb, wb1, yb, ssum, ssq, zp);
  bn_params<<<256, 256, 0, stream>>>(ssum, ssq, gamma1, params1);
  bin_mid<<<6272, 256, 0, stream>>>(yb, params1, beta1, xb);
  bconv_mfma<<<NBLK, 256, 0, stream>>>(xb, wb2, yb, ssum, ssq, zp);
  bn_params<<<256, 256, 0, stream>>>(ssum, ssq, gamma2, params2);
  bn_residual<<<tr, 256, 0, stream>>>(yb, params2, beta2, x, out);
}

// Round 4
// 149.493 us; speedup vs baseline: 1.0730x; 1.0730x over previous
//
#include <hip/hip_runtime.h>
#include <stdint.h>

// Binary BasicBlock: x ->(sign) conv1 ->BN1 ->(sign) conv2 ->BN2 -> +x
// B=64, C=256, H=W=28.  M = 64*784 = 50176 output pixels, N = 256, K = 9*256.
// Convs done as exact i8 MFMA implicit-GEMM (binarized values in {-1,0,1},
// integer accum <= 2304 -> bit-exact vs f32 reference). Conv biases b1/b2
// cancel inside training-mode BN (mean subtraction) and are dropped.
//
// R2/R3: conv restructured to double-buffered 2-phase pipeline (T3 minimum
// recipe): 18 units of (tap, K-half=128), STAGE(u+1) issued before
// COMPUTE(u), one __syncthreads per unit. LDS stays 64KB (2 blocks/CU).

#define HW    784
#define MTOT  50176
#define BM    128
#define BN    128
#define MT    392          // MTOT/BM
#define NBLK  784          // MT * (256/BN)

typedef int   i32x4  __attribute__((ext_vector_type(4)));
typedef short shortx8 __attribute__((ext_vector_type(8)));
typedef float floatx4 __attribute__((ext_vector_type(4)));

typedef __attribute__((address_space(1))) const void gvoid_t;
typedef __attribute__((address_space(3))) void       lvoid_t;

__device__ __forceinline__ void gload16(const void* g, void* l) {
  // async global->LDS, 16B/lane; LDS dest = wave-uniform base + lane*16
  __builtin_amdgcn_global_load_lds((gvoid_t*)g, (lvoid_t*)l, 16, 0, 0);
}

// ---------------------------------------------------------------- zero page
__global__ void zero4k(floatx4* p) { p[threadIdx.x] = (floatx4){0.f, 0.f, 0.f, 0.f}; }

// ---------------------------------------------------------------- binarize w
// w OIHW [256][256][3][3] -> wb [n][k], k = tap*256 + c  (tap = ky*3+kx)
__global__ __launch_bounds__(256) void bin_w(const float* __restrict__ w,
                                             int8_t* __restrict__ wb) {
  int idx = blockIdx.x * 256 + threadIdx.x;      // < 589824
  int n = idx / 2304;
  int k = idx - n * 2304;
  int tap = k >> 8;
  int c = k & 255;
  float v = w[((size_t)n * 256 + c) * 9 + tap];
  wb[idx] = (int8_t)((v > 0.f) - (v < 0.f));
}

// ---------------------------------------------------------------- binarize x
// x NCHW f32 -> xb NHWC i8 via LDS transpose tile (64 m x 64 c)
__global__ __launch_bounds__(256) void bin_x(const float* __restrict__ x,
                                             int8_t* __restrict__ xb) {
  const int mt = blockIdx.x, ct = blockIdx.y;
  __shared__ int8_t sh[64][68];
  const int t = threadIdx.x;
  const int tl = t & 63, th = t >> 6;
#pragma unroll
  for (int i = 0; i < 16; ++i) {
    int cl = th + i * 4;
    int c = ct * 64 + cl;
    int m = mt * 64 + tl;
    int b = m / HW, p = m - b * HW;
    float v = x[((size_t)b * 256 + c) * HW + p];   // coalesced along p
    sh[tl][cl] = (int8_t)((v > 0.f) - (v < 0.f));
  }
  __syncthreads();
#pragma unroll
  for (int i = 0; i < 16; ++i) {
    int ml = th + i * 4;
    xb[(size_t)(mt * 64 + ml) * 256 + ct * 64 + tl] = sh[ml][tl];  // 64B/wave-row
  }
}

// ---------------------------------------------------------------- conv (MFMA)
// xb [M][256] i8 NHWC, wb [256][2304] i8 -> y [M][256] i16 NHWC
// + per-(mtile,wave_m) channel partial sum / sumsq (exact i32, no atomics)
__global__ __launch_bounds__(256, 2) void bconv_mfma(
    const int8_t* __restrict__ xb, const int8_t* __restrict__ wb,
    int16_t* __restrict__ y, int* __restrict__ ssum, int* __restrict__ ssq,
    const int8_t* __restrict__ zp) {
  // double-buffered: per buffer A(128x128)=16KB | B(128x128)=16KB
  __shared__ int8_t lds[2][32768];
  const int tid = threadIdx.x;
  const int lane = tid & 63;
  const int wv = tid >> 6;                      // 4 waves
  const int wm = wv >> 1, wn = wv & 1;          // 2x2 wave grid, 64x64 each
  const int l15 = lane & 15;
  const int l4 = lane >> 4;

  // XCD swizzle: 784 = 8*98 exactly; consecutive mtiles per XCD
  int bid = blockIdx.x;
  int nb = (bid & 7) * (NBLK / 8) + (bid >> 3);
  const int mtile = nb >> 1, ntile = nb & 1;
  const int m0 = mtile * BM, n0 = ntile * BN;

  // staging precompute: per gload call j (0..3), lane's row r = wv*32+j*8+(lane>>3)
  // swizzle offset: block (lane&7) in LDS holds global block ((lane&7)^(r&7));
  // r&7 == lane>>3, so soff is call-independent.
  const int soff = ((lane & 7) ^ (lane >> 3)) << 4;
  int pyv[4], pxv[4], ldso[4];
  size_t pixb[4];
  const int8_t* wsrc[4];
#pragma unroll
  for (int j = 0; j < 4; ++j) {
    int r = wv * 32 + j * 8 + (lane >> 3);
    int m = m0 + r;
    int b = m / HW;
    int p = m - b * HW;
    pyv[j] = p / 28;
    pxv[j] = p - pyv[j] * 28;
    pixb[j] = (size_t)b * HW;
    wsrc[j] = wb + (size_t)(n0 + r) * 2304 + soff;
    ldso[j] = (wv * 32 + j * 8) * 128;          // wave-uniform LDS base (128B rows)
  }

  i32x4 acc[4][4];
#pragma unroll
  for (int a = 0; a < 4; ++a)
#pragma unroll
    for (int b = 0; b < 4; ++b) acc[a][b] = (i32x4){0, 0, 0, 0};

  // unit u = tap*2 + h : tap = u>>1 (0..8), K-half h = u&1 (channel 128-block)
  auto STAGE = [&](int8_t* base, int unit) {
    const int tap = unit >> 1;
    const int coff = (unit & 1) << 7;           // h*128 channel byte offset
    const int dy = tap / 3 - 1, dx = tap % 3 - 1;
#pragma unroll
    for (int j = 0; j < 4; ++j) {
      int yy = pyv[j] + dy, xx = pxv[j] + dx;
      const int8_t* sa = ((unsigned)yy < 28u && (unsigned)xx < 28u)
              ? xb + ((pixb[j] + yy * 28 + xx) << 8) + coff + soff
              : zp + soff;
      gload16(sa, base + ldso[j]);                            // A half-tile
      gload16(wsrc[j] + (unit << 7), base + 16384 + ldso[j]); // B half-tile
    }
  };

  auto COMPUTE = [&](const int8_t* base) {
#pragma unroll
    for (int cc = 0; cc < 2; ++cc) {            // K chunks of 64 within half
      i32x4 af[4], bf[4];
      const int bc = cc * 4 + l4;               // 16B block index 0..7
#pragma unroll
      for (int rb = 0; rb < 4; ++rb) {
        int row = wm * 64 + rb * 16 + l15;
        af[rb] = *(const i32x4*)(base + row * 128 + ((bc ^ (row & 7)) << 4));
      }
#pragma unroll
      for (int nf = 0; nf < 4; ++nf) {
        int row = wn * 64 + nf * 16 + l15;
        bf[nf] = *(const i32x4*)(base + 16384 + row * 128 + ((bc ^ (row & 7)) << 4));
      }
#pragma unroll
      for (int nf = 0; nf < 4; ++nf)
#pragma unroll
        for (int rb = 0; rb < 4; ++rb)
          acc[nf][rb] = __builtin_amdgcn_mfma_i32_16x16x64_i8(af[rb], bf[nf],
                                                              acc[nf][rb], 0, 0, 0);
    }
  };

  // 2-phase pipeline: issue STAGE(u+1) before COMPUTE(u); barrier's implicit
  // vmcnt(0) drain lands after loads had the whole MFMA phase in flight.
  STAGE(lds[0], 0);
  __syncthreads();
  for (int u = 0; u < 18; u += 2) {
    if (u + 1 < 18) STAGE(lds[1], u + 1);
    COMPUTE(lds[0]);
    __syncthreads();
    if (u + 2 < 18) STAGE(lds[0], u + 2);
    COMPUTE(lds[1]);
    __syncthreads();
  }

  // epilogue: store y (i16 NHWC) + exact per-channel partials
  int sum_l[4] = {0, 0, 0, 0}, sq_l[4] = {0, 0, 0, 0};
#pragma unroll
  for (int nf = 0; nf < 4; ++nf) {
    const int n = n0 + wn * 64 + nf * 16 + l15;   // C/D: col = lane&15 (m89)
#pragma unroll
    for (int rb = 0; rb < 4; ++rb) {
      const int mb = m0 + wm * 64 + rb * 16 + l4 * 4;  // row = (lane>>4)*4 + j
#pragma unroll
      for (int j = 0; j < 4; ++j) {
        int v = acc[nf][rb][j];
        y[(size_t)(mb + j) * 256 + n] = (int16_t)v;
        sum_l[nf] += v;
        sq_l[nf] += v * v;                        // <= 16*2304^2, fits i32
      }
    }
  }
#pragma unroll
  for (int nf = 0; nf < 4; ++nf) {
    int s = sum_l[nf], q = sq_l[nf];
    s += __shfl_xor(s, 16); q += __shfl_xor(q, 16);
    s += __shfl_xor(s, 32); q += __shfl_xor(q, 32);
    if (lane < 16) {
      size_t off = (size_t)(mtile * 2 + wm) * 256 + (n0 + wn * 64 + nf * 16 + lane);
      ssum[off] = s;                              // unique writer per slot
      ssq[off] = q;
    }
  }
}

// ---------------------------------------------------------------- BN params
// reduce [MT*2][256] partials -> per-channel mean & gamma*rsqrt(var+eps)
__global__ __launch_bounds__(256) void bn_params(const int* __restrict__ ssum,
                                                 const int* __restrict__ ssq,
                                                 const float* __restrict__ gamma,
                                                 float* __restrict__ params) {
  const int c = blockIdx.x;
  const int t = threadIdx.x;
  long long s = 0, q = 0;
  for (int e = t; e < MT * 2; e += 256) {
    s += ssum[(size_t)e * 256 + c];
    q += ssq[(size_t)e * 256 + c];
  }
  __shared__ long long sh[8];
  for (int off = 32; off; off >>= 1) { s += __shfl_down(s, off); q += __shfl_down(q, off); }
  int wv = t >> 6;
  if ((t & 63) == 0) { sh[wv] = s; sh[wv + 4] = q; }
  __syncthreads();
  if (t == 0) {
    s = sh[0] + sh[1] + sh[2] + sh[3];
    q = sh[4] + sh[5] + sh[6] + sh[7];
    double mean = (double)s / (double)MTOT;
    double var = (double)q / (double)MTOT - mean * mean;
    params[c * 2 + 0] = (float)mean;
    params[c * 2 + 1] = (float)((double)gamma[c] / sqrt(var + 1e-5));
  }
}

// ---------------------------------------------------------------- binarize mid
// xb = sign((y - mean)*inv + beta)   (bias cancels in BN)
__global__ __launch_bounds__(256) void bin_mid(const int16_t* __restrict__ y,
                                               const float* __restrict__ params,
                                               const float* __restrict__ beta,
                                               int8_t* __restrict__ xb) {
  size_t i = ((size_t)blockIdx.x * 256 + threadIdx.x) * 8;
  shortx8 v = *(const shortx8*)(y + i);
  int cb = (int)(i & 255);
  union { int8_t b[8]; unsigned long long u; } o;
#pragma unroll
  for (int j = 0; j < 8; ++j) {
    int c = cb + j;
    float z = ((float)v[j] - params[c * 2]) * params[c * 2 + 1] + beta[c];
    o.b[j] = (int8_t)((z > 0.f) - (z < 0.f));
  }
  *(unsigned long long*)(xb + i) = o.u;
}

// ---------------------------------------------------------------- BN2 + resid
// out NCHW f32 = (y2 - mean)*inv + beta + x ; y2 read NHWC via LDS transpose
__global__ __launch_bounds__(256) void bn_residual(const int16_t* __restrict__ y,
                                                   const float* __restrict__ params,
                                                   const float* __restrict__ beta,
                                                   const float* __restrict__ x,
                                                   float* __restrict__ out) {
  const int mt = blockIdx.x, ct = blockIdx.y;
  __shared__ int16_t sh[64][66];
  const int t = threadIdx.x;
  const int tl = t & 63, th = t >> 6;
#pragma unroll
  for (int i = 0; i < 16; ++i) {
    int ml = th + i * 4;
    sh[ml][tl] = y[(size_t)(mt * 64 + ml) * 256 + ct * 64 + tl];  // coalesced
  }
  __syncthreads();
#pragma unroll
  for (int i = 0; i < 16; ++i) {
    int cl = th + i * 4;
    int c = ct * 64 + cl;
    int m = mt * 64 + tl;
    int b = m / HW, p = m - b * HW;
    size_t oi = ((size_t)b * 256 + c) * HW + p;
    float z = ((float)sh[tl][cl] - params[c * 2]) * params[c * 2 + 1] + beta[c];
    out[oi] = z + x[oi];                         // coalesced along p
  }
}

// ---------------------------------------------------------------- launch
extern "C" void kernel_launch(void* const* d_in, const int* in_sizes, int n_in,
                              void* d_out, int out_size, void* d_ws, size_t ws_size,
                              hipStream_t stream) {
  const float* x      = (const float*)d_in[0];
  const float* w1     = (const float*)d_in[1];
  const float* gamma1 = (const float*)d_in[3];
  const float* beta1  = (const float*)d_in[4];
  const float* w2     = (const float*)d_in[5];
  const float* gamma2 = (const float*)d_in[7];
  const float* beta2  = (const float*)d_in[8];
  float* out = (float*)d_out;

  // ws layout (bytes):
  char* ws = (char*)d_ws;
  int8_t*  zp      = (int8_t*)ws;                       //        0 : 4096 zero page
  int8_t*  wb1     = (int8_t*)(ws + 4096);              //   589824
  int8_t*  wb2     = (int8_t*)(ws + 593920);            //   589824
  float*   params1 = (float*)(ws + 1183744);            //     2048
  float*   params2 = (float*)(ws + 1185792);            //     2048
  int*     ssum    = (int*)(ws + 1187840);              //   802816
  int*     ssq     = (int*)(ws + 1990656);              //   802816
  int8_t*  xb      = (int8_t*)(ws + 2793472);           // 12845056 (reused conv1/conv2 input)
  int16_t* yb      = (int16_t*)(ws + 15638528);         // 25690112 (reused y1/y2)
  if (ws_size < 41328640ull) return;                    // need ~39.4 MiB scratch

  dim3 tr(784, 4);
  zero4k<<<1, 256, 0, stream>>>((floatx4*)zp);          // exactly 4096 B, every launch
  bin_w<<<2304, 256, 0, stream>>>(w1, wb1);
  bin_w<<<2304, 256, 0, stream>>>(w2, wb2);
  bin_x<<<tr, 256, 0, stream>>>(x, xb);
  bconv_mfma<<<NBLK, 256, 0, stream>>>(xb, wb1, yb, ssum, ssq, zp);
  bn_params<<<256, 256, 0, stream>>>(ssum, ssq, gamma1, params1);
  bin_mid<<<6272, 256, 0, stream>>>(yb, params1, beta1, xb);
  bconv_mfma<<<NBLK, 256, 0, stream>>>(xb, wb2, yb, ssum, ssq, zp);
  bn_params<<<256, 256, 0, stream>>>(ssum, ssq, gamma2, params2);
  bn_residual<<<tr, 256, 0, stream>>>(yb, params2, beta2, x, out);
}

// Round 5
// 142.089 us; speedup vs baseline: 1.1289x; 1.0521x over previous
//
#include <hip/hip_runtime.h>
#include <stdint.h>

// Binary BasicBlock: x ->(sign) conv1 ->BN1 ->(sign) conv2 ->BN2 -> +x
// B=64, C=256, H=W=28.  M = 64*784 = 50176 output pixels, N = 256, K = 9*256.
// Convs as exact i8 MFMA implicit-GEMM (binarized {-1,0,1}, int accum <= 2304
// -> bit-exact vs f32). Conv biases cancel in training-mode BN -> dropped.
//
// R4: BM=256 x BN=128 block, 4 waves in 2x2, wave tile 128x64 (85 ops/B LDS
// vs 64 prior), K-unit = 64 (36 units), double-buffered 48KB LDS, 2 blocks/CU.
// Swizzle: 64B rows, chunk' = chunk ^ (row&3) both-sides involution.

#define HW    784
#define MTOT  50176
#define BM    256
#define BN    128
#define MT    196          // MTOT/BM
#define NBLK  392          // MT * (256/BN)

typedef int   i32x4  __attribute__((ext_vector_type(4)));
typedef short shortx8 __attribute__((ext_vector_type(8)));
typedef float floatx4 __attribute__((ext_vector_type(4)));

typedef __attribute__((address_space(1))) const void gvoid_t;
typedef __attribute__((address_space(3))) void       lvoid_t;

__device__ __forceinline__ void gload16(const void* g, void* l) {
  // async global->LDS, 16B/lane; LDS dest = wave-uniform base + lane*16
  __builtin_amdgcn_global_load_lds((gvoid_t*)g, (lvoid_t*)l, 16, 0, 0);
}

// ---------------------------------------------------------------- prep
// block 0: zero the 4KB zero-page; blocks 1..2304: wb1; 2305..4608: wb2
// w OIHW [256][256][3][3] -> wb [n][k], k = tap*256 + c  (tap = ky*3+kx)
__global__ __launch_bounds__(256) void prep(const float* __restrict__ w1,
                                            const float* __restrict__ w2,
                                            int8_t* __restrict__ wb1,
                                            int8_t* __restrict__ wb2,
                                            floatx4* __restrict__ zp) {
  int bid = blockIdx.x;
  if (bid == 0) { zp[threadIdx.x] = (floatx4){0.f, 0.f, 0.f, 0.f}; return; }
  int base = bid - 1;
  const float* w = w1;
  int8_t* wbp = wb1;
  if (base >= 2304) { base -= 2304; w = w2; wbp = wb2; }
  int idx = base * 256 + threadIdx.x;      // < 589824
  int n = idx / 2304;
  int k = idx - n * 2304;
  int tap = k >> 8;
  int c = k & 255;
  float v = w[((size_t)n * 256 + c) * 9 + tap];
  wbp[idx] = (int8_t)((v > 0.f) - (v < 0.f));
}

// ---------------------------------------------------------------- binarize x
// x NCHW f32 -> xb NHWC i8 via LDS transpose tile (64 m x 64 c)
__global__ __launch_bounds__(256) void bin_x(const float* __restrict__ x,
                                             int8_t* __restrict__ xb) {
  const int mt = blockIdx.x, ct = blockIdx.y;
  __shared__ int8_t sh[64][68];
  const int t = threadIdx.x;
  const int tl = t & 63, th = t >> 6;
#pragma unroll
  for (int i = 0; i < 16; ++i) {
    int cl = th + i * 4;
    int c = ct * 64 + cl;
    int m = mt * 64 + tl;
    int b = m / HW, p = m - b * HW;
    float v = x[((size_t)b * 256 + c) * HW + p];   // coalesced along p
    sh[tl][cl] = (int8_t)((v > 0.f) - (v < 0.f));
  }
  __syncthreads();
#pragma unroll
  for (int i = 0; i < 16; ++i) {
    int ml = th + i * 4;
    xb[(size_t)(mt * 64 + ml) * 256 + ct * 64 + tl] = sh[ml][tl];  // 64B/wave-row
  }
}

// ---------------------------------------------------------------- conv (MFMA)
// xb [M][256] i8 NHWC, wb [256][2304] i8 -> y [M][256] i16 NHWC
// + per-(mtile,wave_m) channel partial sum / sumsq (exact i32, no atomics)
__global__ __launch_bounds__(256, 2) void bconv_mfma(
    const int8_t* __restrict__ xb, const int8_t* __restrict__ wb,
    int16_t* __restrict__ y, int* __restrict__ ssum, int* __restrict__ ssq,
    const int8_t* __restrict__ zp) {
  // double-buffered: per buffer A(256x64)=16KB | B(128x64)=8KB
  __shared__ int8_t lds[2][24576];
  const int tid = threadIdx.x;
  const int lane = tid & 63;
  const int wv = tid >> 6;                      // 4 waves
  const int wm = wv >> 1, wn = wv & 1;          // 2x2 grid, wave tile 128x64
  const int l15 = lane & 15;
  const int l4 = lane >> 4;

  // XCD swizzle: 392 = 8*49 exactly; consecutive mtiles per XCD
  int bid = blockIdx.x;
  int nb = (bid & 7) * (NBLK / 8) + (bid >> 3);
  const int mtile = nb >> 1, ntile = nb & 1;
  const int m0 = mtile * BM, n0 = ntile * BN;

  // staging: call j covers rows [j*64, j*64+64); this thread's row
  // r = j*64 + wv*16 + (lane>>2), chunk = lane&3 (16B chunks of 64B rows).
  // Swizzle: LDS[row][c] holds global chunk c^(row&3); row&3 == (lane>>2)&3.
  const int soff = (((lane & 3) ^ ((lane >> 2) & 3)) << 4);
  int pyv[4], pxv[4];
  size_t pixb[4];
  const int8_t* wsrc[2];
#pragma unroll
  for (int j = 0; j < 4; ++j) {
    int r = j * 64 + wv * 16 + (lane >> 2);
    int m = m0 + r;
    int b = m / HW;
    int p = m - b * HW;
    pyv[j] = p / 28;
    pxv[j] = p - pyv[j] * 28;
    pixb[j] = (size_t)b * HW;
  }
#pragma unroll
  for (int jj = 0; jj < 2; ++jj) {
    int r = jj * 64 + wv * 16 + (lane >> 2);
    wsrc[jj] = wb + (size_t)(n0 + r) * 2304 + soff;
  }

  i32x4 acc[8][4];
#pragma unroll
  for (int a = 0; a < 8; ++a)
#pragma unroll
    for (int b = 0; b < 4; ++b) acc[a][b] = (i32x4){0, 0, 0, 0};

  // unit u (0..35): tap = u>>2, K-quarter kq = u&3 (64-ch slice of 256)
  auto STAGE = [&](int8_t* base, int unit) {
    const int tap = unit >> 2;
    const int cb = (unit & 3) << 6;             // kq*64 byte offset in xb row
    const int dy = tap / 3 - 1, dx = tap % 3 - 1;
#pragma unroll
    for (int j = 0; j < 4; ++j) {               // A: 256 rows x 64B
      int yy = pyv[j] + dy, xx = pxv[j] + dx;
      const int8_t* sa = ((unsigned)yy < 28u && (unsigned)xx < 28u)
              ? xb + ((pixb[j] + yy * 28 + xx) << 8) + cb + soff
              : zp + soff;
      gload16(sa, base + j * 4096 + wv * 1024);
    }
#pragma unroll
    for (int jj = 0; jj < 2; ++jj)              // B: 128 rows x 64B
      gload16(wsrc[jj] + unit * 64, base + 16384 + jj * 4096 + wv * 1024);
  };

  auto COMPUTE = [&](const int8_t* base) {
    i32x4 af[8], bf[4];
    const int rsw = ((l4 ^ (l15 & 3)) << 4);    // read-side swizzle (row&3==l15&3)
#pragma unroll
    for (int rb = 0; rb < 8; ++rb)
      af[rb] = *(const i32x4*)(base + (wm * 128 + rb * 16 + l15) * 64 + rsw);
#pragma unroll
    for (int nf = 0; nf < 4; ++nf)
      bf[nf] = *(const i32x4*)(base + 16384 + (wn * 64 + nf * 16 + l15) * 64 + rsw);
#pragma unroll
    for (int nf = 0; nf < 4; ++nf)
#pragma unroll
      for (int rb = 0; rb < 8; ++rb)
        acc[rb][nf] = __builtin_amdgcn_mfma_i32_16x16x64_i8(af[rb], bf[nf],
                                                            acc[rb][nf], 0, 0, 0);
  };

  // 2-phase pipeline: issue STAGE(u+1) before COMPUTE(u); barrier's implicit
  // vmcnt(0) drain lands after loads had the whole MFMA phase in flight.
  STAGE(lds[0], 0);
  __syncthreads();
  for (int u = 0; u < 36; u += 2) {
    if (u + 1 < 36) STAGE(lds[1], u + 1);
    COMPUTE(lds[0]);
    __syncthreads();
    if (u + 2 < 36) STAGE(lds[0], u + 2);
    COMPUTE(lds[1]);
    __syncthreads();
  }

  // epilogue: store y (i16 NHWC) + exact per-channel partials
  int sum_l[4] = {0, 0, 0, 0}, sq_l[4] = {0, 0, 0, 0};
#pragma unroll
  for (int nf = 0; nf < 4; ++nf) {
    const int n = n0 + wn * 64 + nf * 16 + l15;   // C/D: col = lane&15 (m89)
#pragma unroll
    for (int rb = 0; rb < 8; ++rb) {
      const int mb = m0 + wm * 128 + rb * 16 + l4 * 4;  // row = (lane>>4)*4 + j
#pragma unroll
      for (int j = 0; j < 4; ++j) {
        int v = acc[rb][nf][j];
        y[(size_t)(mb + j) * 256 + n] = (int16_t)v;
        sum_l[nf] += v;
        sq_l[nf] += v * v;                        // <= 32*2304^2 = 1.7e8, fits i32
      }
    }
  }
#pragma unroll
  for (int nf = 0; nf < 4; ++nf) {
    int s = sum_l[nf], q = sq_l[nf];
    s += __shfl_xor(s, 16); q += __shfl_xor(q, 16);
    s += __shfl_xor(s, 32); q += __shfl_xor(q, 32);
    if (lane < 16) {
      size_t off = (size_t)(mtile * 2 + wm) * 256 + (n0 + wn * 64 + nf * 16 + lane);
      ssum[off] = s;                              // unique writer per slot
      ssq[off] = q;
    }
  }
}

// ---------------------------------------------------------------- BN params
// reduce [MT*2][256] partials -> per-channel mean & gamma*rsqrt(var+eps)
__global__ __launch_bounds__(256) void bn_params(const int* __restrict__ ssum,
                                                 const int* __restrict__ ssq,
                                                 const float* __restrict__ gamma,
                                                 float* __restrict__ params) {
  const int c = blockIdx.x;
  const int t = threadIdx.x;
  long long s = 0, q = 0;
  for (int e = t; e < MT * 2; e += 256) {        // 392 slot rows of 128 m each
    s += ssum[(size_t)e * 256 + c];
    q += ssq[(size_t)e * 256 + c];
  }
  __shared__ long long sh[8];
  for (int off = 32; off; off >>= 1) { s += __shfl_down(s, off); q += __shfl_down(q, off); }
  int wv = t >> 6;
  if ((t & 63) == 0) { sh[wv] = s; sh[wv + 4] = q; }
  __syncthreads();
  if (t == 0) {
    s = sh[0] + sh[1] + sh[2] + sh[3];
    q = sh[4] + sh[5] + sh[6] + sh[7];
    double mean = (double)s / (double)MTOT;
    double var = (double)q / (double)MTOT - mean * mean;
    params[c * 2 + 0] = (float)mean;
    params[c * 2 + 1] = (float)((double)gamma[c] / sqrt(var + 1e-5));
  }
}

// ---------------------------------------------------------------- binarize mid
// xb = sign((y - mean)*inv + beta)   (bias cancels in BN)
__global__ __launch_bounds__(256) void bin_mid(const int16_t* __restrict__ y,
                                               const float* __restrict__ params,
                                               const float* __restrict__ beta,
                                               int8_t* __restrict__ xb) {
  size_t i = ((size_t)blockIdx.x * 256 + threadIdx.x) * 8;
  shortx8 v = *(const shortx8*)(y + i);
  int cb = (int)(i & 255);
  union { int8_t b[8]; unsigned long long u; } o;
#pragma unroll
  for (int j = 0; j < 8; ++j) {
    int c = cb + j;
    float z = ((float)v[j] - params[c * 2]) * params[c * 2 + 1] + beta[c];
    o.b[j] = (int8_t)((z > 0.f) - (z < 0.f));
  }
  *(unsigned long long*)(xb + i) = o.u;
}

// ---------------------------------------------------------------- BN2 + resid
// out NCHW f32 = (y2 - mean)*inv + beta + x ; y2 read NHWC via LDS transpose
__global__ __launch_bounds__(256) void bn_residual(const int16_t* __restrict__ y,
                                                   const float* __restrict__ params,
                                                   const float* __restrict__ beta,
                                                   const float* __restrict__ x,
                                                   float* __restrict__ out) {
  const int mt = blockIdx.x, ct = blockIdx.y;
  __shared__ int16_t sh[64][66];
  const int t = threadIdx.x;
  const int tl = t & 63, th = t >> 6;
#pragma unroll
  for (int i = 0; i < 16; ++i) {
    int ml = th + i * 4;
    sh[ml][tl] = y[(size_t)(mt * 64 + ml) * 256 + ct * 64 + tl];  // coalesced
  }
  __syncthreads();
#pragma unroll
  for (int i = 0; i < 16; ++i) {
    int cl = th + i * 4;
    int c = ct * 64 + cl;
    int m = mt * 64 + tl;
    int b = m / HW, p = m - b * HW;
    size_t oi = ((size_t)b * 256 + c) * HW + p;
    float z = ((float)sh[tl][cl] - params[c * 2]) * params[c * 2 + 1] + beta[c];
    out[oi] = z + x[oi];                         // coalesced along p
  }
}

// ---------------------------------------------------------------- launch
extern "C" void kernel_launch(void* const* d_in, const int* in_sizes, int n_in,
                              void* d_out, int out_size, void* d_ws, size_t ws_size,
                              hipStream_t stream) {
  const float* x      = (const float*)d_in[0];
  const float* w1     = (const float*)d_in[1];
  const float* gamma1 = (const float*)d_in[3];
  const float* beta1  = (const float*)d_in[4];
  const float* w2     = (const float*)d_in[5];
  const float* gamma2 = (const float*)d_in[7];
  const float* beta2  = (const float*)d_in[8];
  float* out = (float*)d_out;

  // ws layout (bytes):
  char* ws = (char*)d_ws;
  int8_t*  zp      = (int8_t*)ws;                       //        0 : 4096 zero page
  int8_t*  wb1     = (int8_t*)(ws + 4096);              //   589824
  int8_t*  wb2     = (int8_t*)(ws + 593920);            //   589824
  float*   params1 = (float*)(ws + 1183744);            //     2048
  float*   params2 = (float*)(ws + 1185792);            //     2048
  int*     ssum    = (int*)(ws + 1187840);              //   802816 (392*256*4 used)
  int*     ssq     = (int*)(ws + 1990656);              //   802816
  int8_t*  xb      = (int8_t*)(ws + 2793472);           // 12845056 (reused conv1/conv2 input)
  int16_t* yb      = (int16_t*)(ws + 15638528);         // 25690112 (reused y1/y2)
  if (ws_size < 41328640ull) return;                    // need ~39.4 MiB scratch

  dim3 tr(784, 4);
  prep<<<4609, 256, 0, stream>>>(w1, w2, wb1, wb2, (floatx4*)zp);
  bin_x<<<tr, 256, 0, stream>>>(x, xb);
  bconv_mfma<<<NBLK, 256, 0, stream>>>(xb, wb1, yb, ssum, ssq, zp);
  bn_params<<<256, 256, 0, stream>>>(ssum, ssq, gamma1, params1);
  bin_mid<<<6272, 256, 0, stream>>>(yb, params1, beta1, xb);
  bconv_mfma<<<NBLK, 256, 0, stream>>>(xb, wb2, yb, ssum, ssq, zp);
  bn_params<<<256, 256, 0, stream>>>(ssum, ssq, gamma2, params2);
  bn_residual<<<tr, 256, 0, stream>>>(yb, params2, beta2, x, out);
}

// Round 6
// 141.813 us; speedup vs baseline: 1.1311x; 1.0019x over previous
//
#include <hip/hip_runtime.h>
#include <stdint.h>

// Binary BasicBlock: x ->(sign) conv1 ->BN1 ->(sign) conv2 ->BN2 -> +x
// B=64, C=256, H=W=28.  M = 64*784 = 50176 output pixels, N = 256, K = 9*256.
// Convs as exact i8 MFMA implicit-GEMM (binarized {-1,0,1}, int accum <= 2304
// -> bit-exact vs f32). Conv biases cancel in training-mode BN -> dropped.
//
// R6: back to R4 geometry (128x128 tile, 128B rows w/ 8-chunk XOR swizzle —
// measured 0 bank conflicts). Schedule upgraded to counted-vmcnt pipeline
// (T3+T4): raw s_barrier + s_waitcnt vmcnt(8), never draining to 0 in the
// steady loop; prefetch depth 2 units across barriers. T5 setprio on MFMA.

#define HW    784
#define MTOT  50176
#define BM    128
#define BN    128
#define MT    392          // MTOT/BM
#define NBLK  784          // MT * (256/BN)

typedef int   i32x4  __attribute__((ext_vector_type(4)));
typedef short shortx8 __attribute__((ext_vector_type(8)));
typedef float floatx4 __attribute__((ext_vector_type(4)));

typedef __attribute__((address_space(1))) const void gvoid_t;
typedef __attribute__((address_space(3))) void       lvoid_t;

__device__ __forceinline__ void gload16(const void* g, void* l) {
  // async global->LDS, 16B/lane; LDS dest = wave-uniform base + lane*16
  __builtin_amdgcn_global_load_lds((gvoid_t*)g, (lvoid_t*)l, 16, 0, 0);
}

#define BAR() __builtin_amdgcn_s_barrier()
#define VM8() asm volatile("s_waitcnt vmcnt(8)" ::: "memory")
#define VM0() asm volatile("s_waitcnt vmcnt(0)" ::: "memory")

// ---------------------------------------------------------------- prep
// block 0: zero the 4KB zero-page; blocks 1..2304: wb1; 2305..4608: wb2
// w OIHW [256][256][3][3] -> wb [n][k], k = tap*256 + c  (tap = ky*3+kx)
__global__ __launch_bounds__(256) void prep(const float* __restrict__ w1,
                                            const float* __restrict__ w2,
                                            int8_t* __restrict__ wb1,
                                            int8_t* __restrict__ wb2,
                                            floatx4* __restrict__ zp) {
  int bid = blockIdx.x;
  if (bid == 0) { zp[threadIdx.x] = (floatx4){0.f, 0.f, 0.f, 0.f}; return; }
  int base = bid - 1;
  const float* w = w1;
  int8_t* wbp = wb1;
  if (base >= 2304) { base -= 2304; w = w2; wbp = wb2; }
  int idx = base * 256 + threadIdx.x;      // < 589824
  int n = idx / 2304;
  int k = idx - n * 2304;
  int tap = k >> 8;
  int c = k & 255;
  float v = w[((size_t)n * 256 + c) * 9 + tap];
  wbp[idx] = (int8_t)((v > 0.f) - (v < 0.f));
}

// ---------------------------------------------------------------- binarize x
// x NCHW f32 -> xb NHWC i8 via LDS transpose tile (64 m x 64 c)
__global__ __launch_bounds__(256) void bin_x(const float* __restrict__ x,
                                             int8_t* __restrict__ xb) {
  const int mt = blockIdx.x, ct = blockIdx.y;
  __shared__ int8_t sh[64][68];
  const int t = threadIdx.x;
  const int tl = t & 63, th = t >> 6;
#pragma unroll
  for (int i = 0; i < 16; ++i) {
    int cl = th + i * 4;
    int c = ct * 64 + cl;
    int m = mt * 64 + tl;
    int b = m / HW, p = m - b * HW;
    float v = x[((size_t)b * 256 + c) * HW + p];   // coalesced along p
    sh[tl][cl] = (int8_t)((v > 0.f) - (v < 0.f));
  }
  __syncthreads();
#pragma unroll
  for (int i = 0; i < 16; ++i) {
    int ml = th + i * 4;
    xb[(size_t)(mt * 64 + ml) * 256 + ct * 64 + tl] = sh[ml][tl];  // 64B/wave-row
  }
}

// ---------------------------------------------------------------- conv (MFMA)
// xb [M][256] i8 NHWC, wb [256][2304] i8 -> y [M][256] i16 NHWC
// + per-(mtile,wave_m) channel partial sum / sumsq (exact i32, no atomics)
__global__ __launch_bounds__(256, 2) void bconv_mfma(
    const int8_t* __restrict__ xb, const int8_t* __restrict__ wb,
    int16_t* __restrict__ y, int* __restrict__ ssum, int* __restrict__ ssq,
    const int8_t* __restrict__ zp) {
  // double-buffered: per buffer A(128x128)=16KB | B(128x128)=16KB
  __shared__ int8_t lds[2][32768];
  const int tid = threadIdx.x;
  const int lane = tid & 63;
  const int wv = tid >> 6;                      // 4 waves
  const int wm = wv >> 1, wn = wv & 1;          // 2x2 wave grid, 64x64 each
  const int l15 = lane & 15;
  const int l4 = lane >> 4;

  // XCD swizzle: 784 = 8*98 exactly; consecutive mtiles per XCD
  int bid = blockIdx.x;
  int nb = (bid & 7) * (NBLK / 8) + (bid >> 3);
  const int mtile = nb >> 1, ntile = nb & 1;
  const int m0 = mtile * BM, n0 = ntile * BN;

  // staging precompute: per gload call j (0..3), lane's row r = wv*32+j*8+(lane>>3)
  // swizzle offset: block (lane&7) in LDS holds global block ((lane&7)^(r&7));
  // r&7 == lane>>3, so soff is call-independent.
  const int soff = ((lane & 7) ^ (lane >> 3)) << 4;
  int pyv[4], pxv[4], ldso[4];
  size_t pixb[4];
  const int8_t* wsrc[4];
#pragma unroll
  for (int j = 0; j < 4; ++j) {
    int r = wv * 32 + j * 8 + (lane >> 3);
    int m = m0 + r;
    int b = m / HW;
    int p = m - b * HW;
    pyv[j] = p / 28;
    pxv[j] = p - pyv[j] * 28;
    pixb[j] = (size_t)b * HW;
    wsrc[j] = wb + (size_t)(n0 + r) * 2304 + soff;
    ldso[j] = (wv * 32 + j * 8) * 128;          // wave-uniform LDS base (128B rows)
  }

  i32x4 acc[4][4];
#pragma unroll
  for (int a = 0; a < 4; ++a)
#pragma unroll
    for (int b = 0; b < 4; ++b) acc[a][b] = (i32x4){0, 0, 0, 0};

  // unit u = tap*2 + h : tap = u>>1 (0..8), K-half h = u&1 (channel 128-block)
  // STAGE = exactly 8 gload16 per thread (A 4 + B 4) -> vmcnt granularity 8.
  auto STAGE = [&](int8_t* base, int unit) {
    const int tap = unit >> 1;
    const int coff = (unit & 1) << 7;           // h*128 channel byte offset
    const int dy = tap / 3 - 1, dx = tap % 3 - 1;
#pragma unroll
    for (int j = 0; j < 4; ++j) {
      int yy = pyv[j] + dy, xx = pxv[j] + dx;
      const int8_t* sa = ((unsigned)yy < 28u && (unsigned)xx < 28u)
              ? xb + ((pixb[j] + yy * 28 + xx) << 8) + coff + soff
              : zp + soff;
      gload16(sa, base + ldso[j]);                            // A half-tile
      gload16(wsrc[j] + (unit << 7), base + 16384 + ldso[j]); // B half-tile
    }
  };

  auto COMPUTE = [&](const int8_t* base) {
#pragma unroll
    for (int cc = 0; cc < 2; ++cc) {            // K chunks of 64 within half
      i32x4 af[4], bf[4];
      const int bc = cc * 4 + l4;               // 16B block index 0..7
#pragma unroll
      for (int rb = 0; rb < 4; ++rb) {
        int row = wm * 64 + rb * 16 + l15;
        af[rb] = *(const i32x4*)(base + row * 128 + ((bc ^ (row & 7)) << 4));
      }
#pragma unroll
      for (int nf = 0; nf < 4; ++nf) {
        int row = wn * 64 + nf * 16 + l15;
        bf[nf] = *(const i32x4*)(base + 16384 + row * 128 + ((bc ^ (row & 7)) << 4));
      }
      __builtin_amdgcn_s_setprio(1);            // T5: favor MFMA cluster
#pragma unroll
      for (int nf = 0; nf < 4; ++nf)
#pragma unroll
        for (int rb = 0; rb < 4; ++rb)
          acc[nf][rb] = __builtin_amdgcn_mfma_i32_16x16x64_i8(af[rb], bf[nf],
                                                              acc[nf][rb], 0, 0, 0);
      __builtin_amdgcn_s_setprio(0);
    }
  };

  // Counted-vmcnt pipeline (T3+T4): prefetch depth 2, never drain in steady
  // state. Per unit: COMPUTE(u); BAR (all waves done reading buf); STAGE(u+2
  // into freed buf); VM8 (waits u+1's 8 loads, leaves u+2's 8 in flight); BAR.
  STAGE(lds[0], 0);
  STAGE(lds[1], 1);                             // 16 outstanding
  VM8();                                        // unit 0 landed (in-order, m135)
  BAR();
#pragma unroll
  for (int u = 0; u < 18; u += 2) {
    COMPUTE(lds[0]);                            // unit u
    BAR();                                      // done reading lds[0]
    if (u + 2 < 18) { STAGE(lds[0], u + 2); VM8(); BAR(); }
    else            { VM0(); BAR(); }           // u=16: wait unit 17
    COMPUTE(lds[1]);                            // unit u+1
    BAR();                                      // done reading lds[1]
    if (u + 3 < 18) { STAGE(lds[1], u + 3); VM8(); BAR(); }
  }

  // epilogue: store y (i16 NHWC) + exact per-channel partials
  int sum_l[4] = {0, 0, 0, 0}, sq_l[4] = {0, 0, 0, 0};
#pragma unroll
  for (int nf = 0; nf < 4; ++nf) {
    const int n = n0 + wn * 64 + nf * 16 + l15;   // C/D: col = lane&15 (m89)
#pragma unroll
    for (int rb = 0; rb < 4; ++rb) {
      const int mb = m0 + wm * 64 + rb * 16 + l4 * 4;  // row = (lane>>4)*4 + j
#pragma unroll
      for (int j = 0; j < 4; ++j) {
        int v = acc[nf][rb][j];
        y[(size_t)(mb + j) * 256 + n] = (int16_t)v;
        sum_l[nf] += v;
        sq_l[nf] += v * v;                        // <= 16*2304^2, fits i32
      }
    }
  }
#pragma unroll
  for (int nf = 0; nf < 4; ++nf) {
    int s = sum_l[nf], q = sq_l[nf];
    s += __shfl_xor(s, 16); q += __shfl_xor(q, 16);
    s += __shfl_xor(s, 32); q += __shfl_xor(q, 32);
    if (lane < 16) {
      size_t off = (size_t)(mtile * 2 + wm) * 256 + (n0 + wn * 64 + nf * 16 + lane);
      ssum[off] = s;                              // unique writer per slot
      ssq[off] = q;
    }
  }
}

// ---------------------------------------------------------------- BN params
// reduce [MT*2][256] partials -> per-channel mean & gamma*rsqrt(var+eps)
__global__ __launch_bounds__(256) void bn_params(const int* __restrict__ ssum,
                                                 const int* __restrict__ ssq,
                                                 const float* __restrict__ gamma,
                                                 float* __restrict__ params) {
  const int c = blockIdx.x;
  const int t = threadIdx.x;
  long long s = 0, q = 0;
  for (int e = t; e < MT * 2; e += 256) {
    s += ssum[(size_t)e * 256 + c];
    q += ssq[(size_t)e * 256 + c];
  }
  __shared__ long long sh[8];
  for (int off = 32; off; off >>= 1) { s += __shfl_down(s, off); q += __shfl_down(q, off); }
  int wv = t >> 6;
  if ((t & 63) == 0) { sh[wv] = s; sh[wv + 4] = q; }
  __syncthreads();
  if (t == 0) {
    s = sh[0] + sh[1] + sh[2] + sh[3];
    q = sh[4] + sh[5] + sh[6] + sh[7];
    double mean = (double)s / (double)MTOT;
    double var = (double)q / (double)MTOT - mean * mean;
    params[c * 2 + 0] = (float)mean;
    params[c * 2 + 1] = (float)((double)gamma[c] / sqrt(var + 1e-5));
  }
}

// ---------------------------------------------------------------- binarize mid
// xb = sign((y - mean)*inv + beta)   (bias cancels in BN)
__global__ __launch_bounds__(256) void bin_mid(const int16_t* __restrict__ y,
                                               const float* __restrict__ params,
                                               const float* __restrict__ beta,
                                               int8_t* __restrict__ xb) {
  size_t i = ((size_t)blockIdx.x * 256 + threadIdx.x) * 8;
  shortx8 v = *(const shortx8*)(y + i);
  int cb = (int)(i & 255);
  union { int8_t b[8]; unsigned long long u; } o;
#pragma unroll
  for (int j = 0; j < 8; ++j) {
    int c = cb + j;
    float z = ((float)v[j] - params[c * 2]) * params[c * 2 + 1] + beta[c];
    o.b[j] = (int8_t)((z > 0.f) - (z < 0.f));
  }
  *(unsigned long long*)(xb + i) = o.u;
}

// ---------------------------------------------------------------- BN2 + resid
// out NCHW f32 = (y2 - mean)*inv + beta + x ; y2 read NHWC via LDS transpose
__global__ __launch_bounds__(256) void bn_residual(const int16_t* __restrict__ y,
                                                   const float* __restrict__ params,
                                                   const float* __restrict__ beta,
                                                   const float* __restrict__ x,
                                                   float* __restrict__ out) {
  const int mt = blockIdx.x, ct = blockIdx.y;
  __shared__ int16_t sh[64][66];
  const int t = threadIdx.x;
  const int tl = t & 63, th = t >> 6;
#pragma unroll
  for (int i = 0; i < 16; ++i) {
    int ml = th + i * 4;
    sh[ml][tl] = y[(size_t)(mt * 64 + ml) * 256 + ct * 64 + tl];  // coalesced
  }
  __syncthreads();
#pragma unroll
  for (int i = 0; i < 16; ++i) {
    int cl = th + i * 4;
    int c = ct * 64 + cl;
    int m = mt * 64 + tl;
    int b = m / HW, p = m - b * HW;
    size_t oi = ((size_t)b * 256 + c) * HW + p;
    float z = ((float)sh[tl][cl] - params[c * 2]) * params[c * 2 + 1] + beta[c];
    out[oi] = z + x[oi];                         // coalesced along p
  }
}

// ---------------------------------------------------------------- launch
extern "C" void kernel_launch(void* const* d_in, const int* in_sizes, int n_in,
                              void* d_out, int out_size, void* d_ws, size_t ws_size,
                              hipStream_t stream) {
  const float* x      = (const float*)d_in[0];
  const float* w1     = (const float*)d_in[1];
  const float* gamma1 = (const float*)d_in[3];
  const float* beta1  = (const float*)d_in[4];
  const float* w2     = (const float*)d_in[5];
  const float* gamma2 = (const float*)d_in[7];
  const float* beta2  = (const float*)d_in[8];
  float* out = (float*)d_out;

  // ws layout (bytes):
  char* ws = (char*)d_ws;
  int8_t*  zp      = (int8_t*)ws;                       //        0 : 4096 zero page
  int8_t*  wb1     = (int8_t*)(ws + 4096);              //   589824
  int8_t*  wb2     = (int8_t*)(ws + 593920);            //   589824
  float*   params1 = (float*)(ws + 1183744);            //     2048
  float*   params2 = (float*)(ws + 1185792);            //     2048
  int*     ssum    = (int*)(ws + 1187840);              //   802816
  int*     ssq     = (int*)(ws + 1990656);              //   802816
  int8_t*  xb      = (int8_t*)(ws + 2793472);           // 12845056 (reused conv1/conv2 input)
  int16_t* yb      = (int16_t*)(ws + 15638528);         // 25690112 (reused y1/y2)
  if (ws_size < 41328640ull) return;                    // need ~39.4 MiB scratch

  dim3 tr(784, 4);
  prep<<<4609, 256, 0, stream>>>(w1, w2, wb1, wb2, (floatx4*)zp);
  bin_x<<<tr, 256, 0, stream>>>(x, xb);
  bconv_mfma<<<NBLK, 256, 0, stream>>>(xb, wb1, yb, ssum, ssq, zp);
  bn_params<<<256, 256, 0, stream>>>(ssum, ssq, gamma1, params1);
  bin_mid<<<6272, 256, 0, stream>>>(yb, params1, beta1, xb);
  bconv_mfma<<<NBLK, 256, 0, stream>>>(xb, wb2, yb, ssum, ssq, zp);
  bn_params<<<256, 256, 0, stream>>>(ssum, ssq, gamma2, params2);
  bn_residual<<<tr, 256, 0, stream>>>(yb, params2, beta2, x, out);
}